// Round 10
// baseline (195.886 us; speedup 1.0000x reference)
//
#include <hip/hip_runtime.h>
#include <math.h>

#define NCLS 91
#define FDIM 256
#define BINSZ (NCLS * FDIM)          // 23296 floats = 93 KB LDS bins
#define SLICE_PAD (BINSZ + 96)       // slice: bins + 91 counts (padded), dwords
#define MAXPARTS 256

__device__ __forceinline__ float wave_sum64(float ss) {
    #pragma unroll
    for (int m = 1; m < 64; m <<= 1) ss += __shfl_xor(ss, m, 64);
    return ss;
}
__device__ __forceinline__ int wave_sum64_i(int v) {
    #pragma unroll
    for (int m = 1; m < 64; m <<= 1) v += __shfl_xor(v, m, 64);
    return v;
}

// ---- pure-DPP 16-lane butterfly (VALU only, no DS) ----
template <int CTRL>
__device__ __forceinline__ float dpp_addstep(float v) {
    return v + __int_as_float(__builtin_amdgcn_mov_dpp(
        __float_as_int(v), CTRL, 0xf, 0xf, true));
}
__device__ __forceinline__ float group16_sum(float v) {
    v = dpp_addstep<0xB1>(v);    // xor1: quad_perm[1,0,3,2]
    v = dpp_addstep<0x1B>(v);    // xor3: quad_perm[3,2,1,0]
    v = dpp_addstep<0x141>(v);   // xor7: row_half_mirror
    v = dpp_addstep<0x140>(v);   // xor15: row_mirror
    return v;
}

// ---------------- K1: streaming normalize + LDS-binned segment sum ----------------
// R8 post-mortem: every sorted-GATHER variant caps at ~1.6 TB/s effective
// (latency-bound even when L3-resident). This kernel reads features in
// NATURAL order (coalesced streaming, proven ~7 TB/s on this GPU):
// 16 lanes/row, 4 consecutive rows per wave-step (the wave's 16 loads cover
// 4KB contiguous), DPP-only norm reduce, then x*inv scattered into full
// 91x256 LDS bins via independent ds_add_f32 (1 DS instr per row, no chain).
// Block flushes its whole slice with plain float4 streaming stores.
#define MPT 1024
#define WPB (MPT / 64)
extern "C" __global__ void __launch_bounds__(MPT)
mainpass(const float* __restrict__ feats, const int* __restrict__ labels,
         float* __restrict__ slices, int nrows, int nparts)
{
    __shared__ float bins[BINSZ];
    __shared__ unsigned int cnts[96];
    const int tid = threadIdx.x;
    for (int i = tid; i < BINSZ; i += MPT) bins[i] = 0.0f;
    if (tid < 96) cnts[tid] = 0u;
    __syncthreads();

    const int lane = tid & 63;
    const int g = lane >> 4;          // row-in-group 0..3
    const int l16 = lane & 15;        // position-in-row
    const int gwave = blockIdx.x * WPB + (tid >> 6);
    const int total = nparts * WPB;
    const float4* fp = (const float4*)feats;

    for (int grp = gwave; grp * 4 < nrows; grp += total) {
        const int r = grp * 4 + g;
        const bool act = r < nrows;   // nrows%4==0 in practice; groups uniform
        int lab = 0;
        float4 X0, X1, X2, X3;
        if (act) {
            lab = labels[r];
            const float4* rp = fp + (size_t)r * (FDIM / 4);
            X0 = rp[l16];
            X1 = rp[l16 + 16];
            X2 = rp[l16 + 32];
            X3 = rp[l16 + 48];
        } else {
            X0 = X1 = X2 = X3 = make_float4(0.f, 0.f, 0.f, 0.f);
        }
        float ss = 0.f;
        ss = fmaf(X0.x, X0.x, ss); ss = fmaf(X0.y, X0.y, ss);
        ss = fmaf(X0.z, X0.z, ss); ss = fmaf(X0.w, X0.w, ss);
        ss = fmaf(X1.x, X1.x, ss); ss = fmaf(X1.y, X1.y, ss);
        ss = fmaf(X1.z, X1.z, ss); ss = fmaf(X1.w, X1.w, ss);
        ss = fmaf(X2.x, X2.x, ss); ss = fmaf(X2.y, X2.y, ss);
        ss = fmaf(X2.z, X2.z, ss); ss = fmaf(X2.w, X2.w, ss);
        ss = fmaf(X3.x, X3.x, ss); ss = fmaf(X3.y, X3.y, ss);
        ss = fmaf(X3.z, X3.z, ss); ss = fmaf(X3.w, X3.w, ss);
        ss = group16_sum(ss);                       // 4 DPP adds, pure VALU
        const float inv = 1.0f / fmaxf(sqrtf(ss), 1e-12f);
        if (act) {
            float* b = bins + lab * FDIM + l16 * 4;  // dim d = l16*4 + 64k + j
            unsafeAtomicAdd(b + 0,       X0.x * inv);
            unsafeAtomicAdd(b + 1,       X0.y * inv);
            unsafeAtomicAdd(b + 2,       X0.z * inv);
            unsafeAtomicAdd(b + 3,       X0.w * inv);
            unsafeAtomicAdd(b + 64 + 0,  X1.x * inv);
            unsafeAtomicAdd(b + 64 + 1,  X1.y * inv);
            unsafeAtomicAdd(b + 64 + 2,  X1.z * inv);
            unsafeAtomicAdd(b + 64 + 3,  X1.w * inv);
            unsafeAtomicAdd(b + 128 + 0, X2.x * inv);
            unsafeAtomicAdd(b + 128 + 1, X2.y * inv);
            unsafeAtomicAdd(b + 128 + 2, X2.z * inv);
            unsafeAtomicAdd(b + 128 + 3, X2.w * inv);
            unsafeAtomicAdd(b + 192 + 0, X3.x * inv);
            unsafeAtomicAdd(b + 192 + 1, X3.y * inv);
            unsafeAtomicAdd(b + 192 + 2, X3.z * inv);
            unsafeAtomicAdd(b + 192 + 3, X3.w * inv);
            if (l16 == 0) atomicAdd(&cnts[lab], 1u);
        }
    }

    __syncthreads();
    // full-slice streaming flush (plain stores, no atomics)
    float* sl = slices + (size_t)blockIdx.x * SLICE_PAD;
    float4* sl4 = (float4*)sl;
    const float4* b4 = (const float4*)bins;
    for (int i = tid; i < BINSZ / 4; i += MPT) sl4[i] = b4[i];
    unsigned int* slc = (unsigned int*)(sl + BINSZ);
    if (tid < 96) slc[tid] = cnts[tid];
}

// ---------------- bool / scalar dtype detection ----------------
__device__ int detect_bool_enc(const void* p) {
    const unsigned int* u = (const unsigned int*)p;
    bool i32ok = true, f32ok = true;
    for (int i = 0; i < 22; ++i) {
        unsigned int w = u[i];
        if (w > 1u) i32ok = false;
        if (w != 0u && w != 0x3F800000u) f32ok = false;
    }
    return i32ok ? 1 : (f32ok ? 2 : 0);
}
__device__ bool read_bool(const void* p, int enc, int i) {
    if (enc == 1) return ((const unsigned int*)p)[i] != 0u;
    if (enc == 2) return ((const float*)p)[i] != 0.0f;
    return ((const unsigned char*)p)[i] != 0;
}
__device__ int read_step(const void* p) {
    unsigned int w = ((const unsigned int*)p)[0];
    int iv = (int)w;
    if (iv >= 0 && iv < 16777216) return iv;
    return (int)__uint_as_float(w);
}

// ---------------- K2: reduce slices + per-class finalize ----------------
extern "C" __global__ void __launch_bounds__(FDIM)
finalize(const float* __restrict__ slices, int nparts,
         const float* __restrict__ protos, const void* __restrict__ p_init,
         const float* __restrict__ p_var, const float* __restrict__ shadow,
         const void* __restrict__ s_init, const int* __restrict__ p_count,
         const void* __restrict__ p_step, float* __restrict__ out)
{
    const int c = blockIdx.x;
    const int d = threadIdx.x;

    __shared__ int enc_pi, enc_si;
    __shared__ float red[FDIM / 64];
    __shared__ int credi[FDIM / 64];
    __shared__ float s_upd;
    __shared__ unsigned int s_cnt;
    if (d == 0) { enc_pi = detect_bool_enc(p_init); enc_si = detect_bool_enc(s_init); }

    // counts: thread d reads partial d's count, block-reduce
    int cpart = 0;
    if (d < nparts)
        cpart = (int)((const unsigned int*)(slices + (size_t)d * SLICE_PAD + BINSZ))[c];
    int cw = wave_sum64_i(cpart);
    if ((d & 63) == 0) credi[d >> 6] = cw;
    __syncthreads();
    if (d == 0) s_cnt = (unsigned int)(credi[0] + credi[1] + credi[2] + credi[3]);

    // sums: 256-way slice reduction, unroll-8 (independent loads in flight)
    const int slot = c * FDIM + d;
    float a0 = 0.f, a1 = 0.f, a2 = 0.f, a3 = 0.f, a4 = 0.f, a5 = 0.f, a6 = 0.f, a7 = 0.f;
    int p = 0;
    for (; p + 7 < nparts; p += 8) {
        a0 += slices[(size_t)(p + 0) * SLICE_PAD + slot];
        a1 += slices[(size_t)(p + 1) * SLICE_PAD + slot];
        a2 += slices[(size_t)(p + 2) * SLICE_PAD + slot];
        a3 += slices[(size_t)(p + 3) * SLICE_PAD + slot];
        a4 += slices[(size_t)(p + 4) * SLICE_PAD + slot];
        a5 += slices[(size_t)(p + 5) * SLICE_PAD + slot];
        a6 += slices[(size_t)(p + 6) * SLICE_PAD + slot];
        a7 += slices[(size_t)(p + 7) * SLICE_PAD + slot];
    }
    for (; p < nparts; ++p) a0 += slices[(size_t)p * SLICE_PAD + slot];
    const float sum = ((a0 + a1) + (a2 + a3)) + ((a4 + a5) + (a6 + a7));
    __syncthreads();

    const unsigned int cnt = s_cnt;
    const bool present = cnt > 0u;
    const float cls = sum / fmaxf((float)cnt, 1.0f);
    const float oldp = protos[c * FDIM + d];

    const float diff = cls - oldp;
    float ds = wave_sum64(diff * diff);
    if ((d & 63) == 0) red[d >> 6] = ds;
    __syncthreads();
    if (d == 0) s_upd = sqrtf(red[0] + red[1] + red[2] + red[3] + 1e-24f);
    __syncthreads();
    const float upd_mag = s_upd;

    const bool  init  = read_bool(p_init, enc_pi, c);
    const bool  sinit = read_bool(s_init, enc_si, c);
    const float var   = p_var[c];
    const int   step  = read_step(p_step);

    const float progress = fminf(1.0f, (float)step * (1.0f / 2000.0f));
    const float mom = init ? (0.99f + 0.009f * expf(-var) * progress) : 0.99f;

    const float ema   = mom * oldp + (1.0f - mom) * cls;
    const float newp  = present ? (init ? ema : cls) : oldp;

    const float sh     = shadow[c * FDIM + d];
    const float sh_ema = 0.9999f * sh + 0.0001f * newp;
    const float newsh  = present ? (sinit ? sh_ema : newp) : sh;

    const int O1 = NCLS * FDIM;
    const int O2 = O1 + NCLS;
    const int O3 = O2 + NCLS * FDIM;
    const int O4 = O3 + NCLS;
    const int O5 = O4 + NCLS;

    out[c * FDIM + d]       = newp;
    out[O2 + c * FDIM + d]  = newsh;
    if (d == 0) {
        const float newvar = (present && init) ? (0.99f * var + 0.01f * upd_mag) : var;
        out[O1 + c] = newvar;
        out[O3 + c] = (init || present)  ? 1.0f : 0.0f;
        out[O4 + c] = (sinit || present) ? 1.0f : 0.0f;
        out[O5 + c] = (float)(p_count[c] + (present ? 1 : 0));
    }
}

extern "C" void kernel_launch(void* const* d_in, const int* in_sizes, int n_in,
                              void* d_out, int out_size, void* d_ws, size_t ws_size,
                              hipStream_t stream) {
    const float* feats  = (const float*)d_in[0];
    const int*   labels = (const int*)d_in[1];
    const float* protos = (const float*)d_in[2];
    const void*  p_init = d_in[3];
    const float* p_var  = (const float*)d_in[4];
    const float* shadow = (const float*)d_in[5];
    const void*  s_init = d_in[6];
    const int*   p_cnt  = (const int*)d_in[7];
    const void*  p_step = d_in[8];
    const int nrows = in_sizes[1];

    int nparts = (int)(ws_size / ((size_t)SLICE_PAD * 4));
    if (nparts > MAXPARTS) nparts = MAXPARTS;
    if (nparts < 1) nparts = 1;

    float* slices = (float*)d_ws;
    mainpass<<<nparts, MPT, 0, stream>>>(feats, labels, slices, nrows, nparts);
    finalize<<<NCLS, FDIM, 0, stream>>>(slices, nparts, protos, p_init, p_var,
                                        shadow, s_init, p_cnt, p_step, (float*)d_out);
}

// Round 11
// 95.835 us; speedup vs baseline: 2.0440x; 2.0440x over previous
//
#include <hip/hip_runtime.h>
#include <math.h>

#define NCLS 91
#define FDIM 256
#define NB   256                   // mainpass blocks (= partials)
#define BINSZ (NCLS * FDIM)

typedef float f32x4 __attribute__((ext_vector_type(4)));
typedef short short8 __attribute__((ext_vector_type(8)));

__device__ __forceinline__ float wave_sum64(float ss) {
    #pragma unroll
    for (int m = 1; m < 64; m <<= 1) ss += __shfl_xor(ss, m, 64);
    return ss;
}

// pure-DPP 16-lane butterfly (VALU only) — verified in R9
template <int CTRL>
__device__ __forceinline__ float dpp_addstep(float v) {
    return v + __int_as_float(__builtin_amdgcn_mov_dpp(
        __float_as_int(v), CTRL, 0xf, 0xf, true));
}
__device__ __forceinline__ float group16_sum(float v) {
    v = dpp_addstep<0xB1>(v);
    v = dpp_addstep<0x1B>(v);
    v = dpp_addstep<0x141>(v);
    v = dpp_addstep<0x140>(v);
    return v;
}

__device__ __forceinline__ unsigned short f2bf(float x) {   // RNE f32->bf16
    unsigned u = __float_as_uint(x);
    return (unsigned short)((u + 0x7FFFu + ((u >> 16) & 1u)) >> 16);
}

// ---------------- K1: streaming normalize + one-hot MFMA segment-sum ----------------
// S[c,d] = sum_k onehot[c,k] * fnorm[k,d] as MFMA: per-class accumulation happens
// in AGPRs — ZERO per-row LDS atomics (the ~205cy/instr wall of R0/R1/R2/R9) and
// ZERO gather (the 80us latency wall of R3-R8). 16 waves each own a 16-dim slice,
// 6 c-tiles (96>=91 classes) of f32x4 acc. Chunks of 64 rows staged bf16 in LDS
// (row stride 260 u16 -> 2-way-free ds_read_u16 B-frags). Labels staged as bytes.
#define MPT 1024
#define CHUNK 64
#define ROWSTRIDE 260              // u16 units; 520B, qword-stride 65

extern "C" __global__ void __launch_bounds__(MPT)
mfma_main(const float* __restrict__ feats, const int* __restrict__ labels,
          float* __restrict__ slices, unsigned int* __restrict__ cnts_ws,
          int nrows, int rpb)
{
    __shared__ __align__(16) unsigned short sdat[CHUNK * ROWSTRIDE];
    __shared__ __align__(8)  unsigned char  slbl[CHUNK];
    __shared__ unsigned int scnt[96];

    const int tid  = threadIdx.x;
    const int lane = tid & 63;
    const int w    = tid >> 6;        // wave 0..15 -> d-tile
    const int l16  = lane & 15;
    const int g    = lane >> 4;       // lane group 0..3
    const int d0   = w * 16;

    if (tid < 96) scnt[tid] = 0u;
    __syncthreads();

    const int row0 = blockIdx.x * rpb;
    const int nch  = rpb / CHUNK;

    f32x4 acc[6];
    #pragma unroll
    for (int ct = 0; ct < 6; ++ct) acc[ct] = (f32x4){0.f, 0.f, 0.f, 0.f};

    // prefetch chunk 0: this lane stages row (w*4+g), dims l16*16..+15
    float4 pf0, pf1, pf2, pf3;
    int plab;
    {
        const int r = row0 + w * 4 + g;
        const bool act = r < nrows;
        if (act) {
            const float4* bp = (const float4*)(feats + (size_t)r * FDIM + l16 * 16);
            pf0 = bp[0]; pf1 = bp[1]; pf2 = bp[2]; pf3 = bp[3];
            plab = labels[r];
        } else {
            pf0 = pf1 = pf2 = pf3 = make_float4(0.f, 0.f, 0.f, 0.f);
            plab = 255;               // matches no c-tile
        }
    }

    for (int ch = 0; ch < nch; ++ch) {
        // ---- normalize prefetched row (f32), cvt bf16, write LDS ----
        const int r_loc = w * 4 + g;
        float ss = 0.f;
        ss = fmaf(pf0.x, pf0.x, ss); ss = fmaf(pf0.y, pf0.y, ss);
        ss = fmaf(pf0.z, pf0.z, ss); ss = fmaf(pf0.w, pf0.w, ss);
        ss = fmaf(pf1.x, pf1.x, ss); ss = fmaf(pf1.y, pf1.y, ss);
        ss = fmaf(pf1.z, pf1.z, ss); ss = fmaf(pf1.w, pf1.w, ss);
        ss = fmaf(pf2.x, pf2.x, ss); ss = fmaf(pf2.y, pf2.y, ss);
        ss = fmaf(pf2.z, pf2.z, ss); ss = fmaf(pf2.w, pf2.w, ss);
        ss = fmaf(pf3.x, pf3.x, ss); ss = fmaf(pf3.y, pf3.y, ss);
        ss = fmaf(pf3.z, pf3.z, ss); ss = fmaf(pf3.w, pf3.w, ss);
        ss = group16_sum(ss);                         // row total over 16 lanes
        const float inv = 1.0f / fmaxf(sqrtf(ss), 1e-12f);

        unsigned long long* q = (unsigned long long*)sdat + (size_t)r_loc * 65 + l16 * 4;
        {
            float e[16] = {pf0.x, pf0.y, pf0.z, pf0.w, pf1.x, pf1.y, pf1.z, pf1.w,
                           pf2.x, pf2.y, pf2.z, pf2.w, pf3.x, pf3.y, pf3.z, pf3.w};
            #pragma unroll
            for (int t = 0; t < 4; ++t) {
                unsigned long long v =
                    (unsigned long long)f2bf(e[4 * t + 0])
                  | ((unsigned long long)f2bf(e[4 * t + 1]) << 16)
                  | ((unsigned long long)f2bf(e[4 * t + 2]) << 32)
                  | ((unsigned long long)f2bf(e[4 * t + 3]) << 48);
                q[t] = v;
            }
        }
        if (l16 == 0) {
            slbl[r_loc] = (unsigned char)plab;
            if (plab < 96) atomicAdd(&scnt[plab], 1u);   // native u32 LDS atomic
        }

        // ---- issue next chunk's loads (hidden under MFMA phase) ----
        if (ch + 1 < nch) {
            const int r = row0 + (ch + 1) * CHUNK + w * 4 + g;
            const bool act = r < nrows;
            if (act) {
                const float4* bp = (const float4*)(feats + (size_t)r * FDIM + l16 * 16);
                pf0 = bp[0]; pf1 = bp[1]; pf2 = bp[2]; pf3 = bp[3];
                plab = labels[r];
            } else {
                pf0 = pf1 = pf2 = pf3 = make_float4(0.f, 0.f, 0.f, 0.f);
                plab = 255;
            }
        }
        __syncthreads();

        // ---- MFMA over the staged chunk: 2 K-steps of 32 rows ----
        #pragma unroll
        for (int s = 0; s < 2; ++s) {
            const int kbase = s * 32 + g * 8;
            const unsigned long long lb =
                *(const unsigned long long*)&slbl[kbase];   // 8 label bytes
            int la[8];
            #pragma unroll
            for (int j = 0; j < 8; ++j) la[j] = (int)((lb >> (8 * j)) & 0xFFu);

            short8 b;
            #pragma unroll
            for (int j = 0; j < 8; ++j)
                b[j] = (short)sdat[(size_t)(kbase + j) * ROWSTRIDE + d0 + l16];

            #pragma unroll
            for (int ct = 0; ct < 6; ++ct) {
                const int c = ct * 16 + l16;     // A row m = lane&15
                short8 a;
                #pragma unroll
                for (int j = 0; j < 8; ++j)
                    a[j] = (la[j] == c) ? (short)0x3F80 : (short)0;
                acc[ct] = __builtin_amdgcn_mfma_f32_16x16x32_bf16(a, b, acc[ct], 0, 0, 0);
            }
        }
        __syncthreads();
    }

    // ---- epilogue: C layout col=lane&15 (d), row=(lane>>4)*4+reg (c) [m89-verified]
    #pragma unroll
    for (int ct = 0; ct < 6; ++ct) {
        #pragma unroll
        for (int reg = 0; reg < 4; ++reg) {
            const int c = ct * 16 + g * 4 + reg;
            const int d = d0 + l16;
            if (c < NCLS)
                slices[(size_t)(c * FDIM + d) * NB + blockIdx.x] = acc[ct][reg];
        }
    }
    __syncthreads();
    if (tid < 96) cnts_ws[(size_t)tid * NB + blockIdx.x] = scnt[tid];
}

// ---------------- bool / scalar dtype detection ----------------
__device__ int detect_bool_enc(const void* p) {
    const unsigned int* u = (const unsigned int*)p;
    bool i32ok = true, f32ok = true;
    for (int i = 0; i < 22; ++i) {
        unsigned int w = u[i];
        if (w > 1u) i32ok = false;
        if (w != 0u && w != 0x3F800000u) f32ok = false;
    }
    return i32ok ? 1 : (f32ok ? 2 : 0);
}
__device__ bool read_bool(const void* p, int enc, int i) {
    if (enc == 1) return ((const unsigned int*)p)[i] != 0u;
    if (enc == 2) return ((const float*)p)[i] != 0.0f;
    return ((const unsigned char*)p)[i] != 0;
}
__device__ int read_step(const void* p) {
    unsigned int w = ((const unsigned int*)p)[0];
    int iv = (int)w;
    if (iv >= 0 && iv < 16777216) return iv;
    return (int)__uint_as_float(w);
}

// ---------------- K2: reduce slices (coalesced per-thread runs) + finalize ----------------
extern "C" __global__ void __launch_bounds__(FDIM)
finalize(const float* __restrict__ slices, const unsigned int* __restrict__ cnts_ws,
         const float* __restrict__ protos, const void* __restrict__ p_init,
         const float* __restrict__ p_var, const float* __restrict__ shadow,
         const void* __restrict__ s_init, const int* __restrict__ p_count,
         const void* __restrict__ p_step, float* __restrict__ out)
{
    const int c = blockIdx.x;
    const int d = threadIdx.x;

    __shared__ int enc_pi, enc_si;
    __shared__ float red[FDIM / 64];
    __shared__ float s_upd;
    __shared__ unsigned int s_cnt;
    if (d == 0) { enc_pi = detect_bool_enc(p_init); enc_si = detect_bool_enc(s_init); }

    // count: 256 contiguous u32 for this class; wave 0 reduces
    if (d < 64) {
        const uint4 cv = ((const uint4*)(cnts_ws + (size_t)c * NB))[d];
        unsigned int me = cv.x + cv.y + cv.z + cv.w;
        float mf = (float)me;
        mf = wave_sum64(mf);
        if (d == 0) s_cnt = (unsigned int)(mf + 0.5f);
    }

    // sum: this slot's 256 partials are CONTIGUOUS (slot-major layout)
    const float4* p4 = (const float4*)(slices + (size_t)(c * FDIM + d) * NB);
    float a0 = 0.f, a1 = 0.f, a2 = 0.f, a3 = 0.f;
    #pragma unroll 4
    for (int i = 0; i < NB / 4; i += 4) {
        const float4 v0 = p4[i + 0], v1 = p4[i + 1], v2 = p4[i + 2], v3 = p4[i + 3];
        a0 += v0.x + v0.y + v0.z + v0.w;
        a1 += v1.x + v1.y + v1.z + v1.w;
        a2 += v2.x + v2.y + v2.z + v2.w;
        a3 += v3.x + v3.y + v3.z + v3.w;
    }
    const float sum = (a0 + a1) + (a2 + a3);
    __syncthreads();

    const unsigned int cnt = s_cnt;
    const bool present = cnt > 0u;
    const float cls = sum / fmaxf((float)cnt, 1.0f);
    const float oldp = protos[c * FDIM + d];

    const float diff = cls - oldp;
    float ds = wave_sum64(diff * diff);
    if ((d & 63) == 0) red[d >> 6] = ds;
    __syncthreads();
    if (d == 0) s_upd = sqrtf(red[0] + red[1] + red[2] + red[3] + 1e-24f);
    __syncthreads();
    const float upd_mag = s_upd;

    const bool  init  = read_bool(p_init, enc_pi, c);
    const bool  sinit = read_bool(s_init, enc_si, c);
    const float var   = p_var[c];
    const int   step  = read_step(p_step);

    const float progress = fminf(1.0f, (float)step * (1.0f / 2000.0f));
    const float mom = init ? (0.99f + 0.009f * expf(-var) * progress) : 0.99f;

    const float ema   = mom * oldp + (1.0f - mom) * cls;
    const float newp  = present ? (init ? ema : cls) : oldp;

    const float sh     = shadow[c * FDIM + d];
    const float sh_ema = 0.9999f * sh + 0.0001f * newp;
    const float newsh  = present ? (sinit ? sh_ema : newp) : sh;

    const int O1 = NCLS * FDIM;
    const int O2 = O1 + NCLS;
    const int O3 = O2 + NCLS * FDIM;
    const int O4 = O3 + NCLS;
    const int O5 = O4 + NCLS;

    out[c * FDIM + d]       = newp;
    out[O2 + c * FDIM + d]  = newsh;
    if (d == 0) {
        const float newvar = (present && init) ? (0.99f * var + 0.01f * upd_mag) : var;
        out[O1 + c] = newvar;
        out[O3 + c] = (init || present)  ? 1.0f : 0.0f;
        out[O4 + c] = (sinit || present) ? 1.0f : 0.0f;
        out[O5 + c] = (float)(p_count[c] + (present ? 1 : 0));
    }
}

extern "C" void kernel_launch(void* const* d_in, const int* in_sizes, int n_in,
                              void* d_out, int out_size, void* d_ws, size_t ws_size,
                              hipStream_t stream) {
    const float* feats  = (const float*)d_in[0];
    const int*   labels = (const int*)d_in[1];
    const float* protos = (const float*)d_in[2];
    const void*  p_init = d_in[3];
    const float* p_var  = (const float*)d_in[4];
    const float* shadow = (const float*)d_in[5];
    const void*  s_init = d_in[6];
    const int*   p_cnt  = (const int*)d_in[7];
    const void*  p_step = d_in[8];
    const int nrows = in_sizes[1];

    // rows per block: multiple of 64, covering nrows with 256 blocks
    int rpb = (nrows + NB - 1) / NB;
    rpb = ((rpb + CHUNK - 1) / CHUNK) * CHUNK;

    float*        slices  = (float*)d_ws;                       // [23296][256]
    unsigned int* cnts_ws = (unsigned int*)d_ws + BINSZ * NB;   // [96][256]

    mfma_main<<<NB, MPT, 0, stream>>>(feats, labels, slices, cnts_ws, nrows, rpb);
    finalize<<<NCLS, FDIM, 0, stream>>>(slices, cnts_ws, protos, p_init, p_var,
                                        shadow, s_init, p_cnt, p_step, (float*)d_out);
}